// Round 1
// baseline (253.826 us; speedup 1.0000x reference)
//
#include <hip/hip_runtime.h>
#include <math.h>

#define B_ 2048
#define S_ 16
#define D_ 768
#define H1_ 256
#define H2_ 128
#define P_ 126

static constexpr float EPS = 1e-6f;
static constexpr float BN_EPS = 1e-5f;
static constexpr float L_PCSL = 50.0f;
static constexpr float L_DANN = 0.5f;

// ---------------- K1: f[b,d] = mean over s of features[b,s,d] ----------------
// 2048 blocks x 192 threads, float4 over D=768.
__global__ __launch_bounds__(192) void k_mean(const float* __restrict__ feat,
                                              float* __restrict__ f) {
    int b = blockIdx.x;
    int t = threadIdx.x;  // 0..191
    const float4* src = (const float4*)(feat + (size_t)b * S_ * D_);
    float4 acc = make_float4(0.f, 0.f, 0.f, 0.f);
#pragma unroll
    for (int s = 0; s < S_; ++s) {
        float4 v = src[s * (D_ / 4) + t];
        acc.x += v.x; acc.y += v.y; acc.z += v.z; acc.w += v.w;
    }
    const float inv = 1.0f / (float)S_;
    acc.x *= inv; acc.y *= inv; acc.z *= inv; acc.w *= inv;
    ((float4*)(f + (size_t)b * D_))[t] = acc;
}

// ---------------- K2: per-patient centroid, sq, count (deterministic scan) ----
// 126 blocks x 192 threads.
__global__ __launch_bounds__(192) void k_centroid(const float* __restrict__ f,
                                                  const int* __restrict__ pid,
                                                  float* __restrict__ cent,
                                                  float* __restrict__ sq,
                                                  float* __restrict__ counts) {
    __shared__ int sid[B_];
    __shared__ float wred[3];
    int p = blockIdx.x;
    int t = threadIdx.x;
    for (int i = t; i < B_; i += blockDim.x) sid[i] = pid[i];
    __syncthreads();
    float4 acc = make_float4(0.f, 0.f, 0.f, 0.f);
    int cnt = 0;
    for (int b = 0; b < B_; ++b) {
        if (sid[b] == p) {
            ++cnt;
            float4 v = ((const float4*)(f + (size_t)b * D_))[t];
            acc.x += v.x; acc.y += v.y; acc.z += v.z; acc.w += v.w;
        }
    }
    float invc = 1.0f / (float)(cnt > 0 ? cnt : 1);
    acc.x *= invc; acc.y *= invc; acc.z *= invc; acc.w *= invc;
    ((float4*)(cent + (size_t)p * D_))[t] = acc;
    float ss = acc.x * acc.x + acc.y * acc.y + acc.z * acc.z + acc.w * acc.w;
    for (int off = 32; off; off >>= 1) ss += __shfl_down(ss, off, 64);
    if ((t & 63) == 0) wred[t >> 6] = ss;
    __syncthreads();
    if (t == 0) {
        sq[p] = wred[0] + wred[1] + wred[2];
        counts[p] = (float)cnt;
    }
}

// ---------------- K3: between + mapped-id table (single block) ---------------
// between = n_present * sum(sq) - ||sum_p centroid_p||^2  (absent centroids are 0)
__global__ __launch_bounds__(256) void k_between(const float* __restrict__ cent,
                                                 const float* __restrict__ sq,
                                                 const float* __restrict__ counts,
                                                 float* __restrict__ scal,
                                                 int* __restrict__ mapped) {
    int t = threadIdx.x;
    float acc = 0.f;
    for (int d = t; d < D_; d += 256) {
        float cs = 0.f;
        for (int p = 0; p < P_; ++p) cs += cent[(size_t)p * D_ + d];
        acc += cs * cs;
    }
    for (int off = 32; off; off >>= 1) acc += __shfl_down(acc, off, 64);
    __shared__ float wred[4];
    if ((t & 63) == 0) wred[t >> 6] = acc;
    __syncthreads();
    if (t == 0) {
        float B2 = wred[0] + wred[1] + wred[2] + wred[3];
        float ssq = 0.f;
        int run = 0;
        for (int p = 0; p < P_; ++p) {
            bool pres = counts[p] > 0.f;
            mapped[p] = pres ? run : -1;
            if (pres) { run++; ssq += sq[p]; }
        }
        scal[1] = (float)run * ssq - B2;  // between
    }
}

// ---------------- K4: within = sum((f - cent[pid])^2) ------------------------
__global__ __launch_bounds__(256) void k_within(const float* __restrict__ f,
                                                const int* __restrict__ pid,
                                                const float* __restrict__ cent,
                                                float* __restrict__ scal) {
    const int total = B_ * D_ / 4;
    int idx = blockIdx.x * blockDim.x + threadIdx.x;
    float accs = 0.f;
    for (int i = idx; i < total; i += gridDim.x * blockDim.x) {
        int b = i / (D_ / 4);
        int dd = i % (D_ / 4);
        float4 fv = ((const float4*)f)[i];
        float4 cv = ((const float4*)(cent + (size_t)pid[b] * D_))[dd];
        float dx = fv.x - cv.x, dy = fv.y - cv.y, dz = fv.z - cv.z, dw = fv.w - cv.w;
        accs += dx * dx + dy * dy + dz * dz + dw * dw;
    }
    for (int off = 32; off; off >>= 1) accs += __shfl_down(accs, off, 64);
    __shared__ float wred[4];
    if ((threadIdx.x & 63) == 0) wred[threadIdx.x >> 6] = accs;
    __syncthreads();
    if (threadIdx.x == 0) atomicAdd(&scal[0], wred[0] + wred[1] + wred[2] + wred[3]);
}

// ---------------- K5/K6: fp32 tiled GEMM + bias + BN(eval) + ReLU ------------
// C[M,N] = A[M,K] @ W[K,N]; out = relu((C + bias) * (gamma/sqrt(1+BN_EPS)) + beta)
// 64x64 tile, BK=16, 256 threads, 4x4 per thread.
template <int KDIM>
__global__ __launch_bounds__(256) void k_gemm_bn_relu(const float* __restrict__ A,
                                                      const float* __restrict__ W,
                                                      const float* __restrict__ bias,
                                                      const float* __restrict__ gamma,
                                                      const float* __restrict__ beta,
                                                      float* __restrict__ out, int N) {
    constexpr int BK = 16;
    __shared__ float As[BK][64 + 4];  // As[k][m]
    __shared__ float Bs[BK][64 + 4];  // Bs[k][n]
    int tid = threadIdx.x;
    int tx = tid & 15, ty = tid >> 4;
    int bm = blockIdx.x * 64, bn = blockIdx.y * 64;
    float c[4][4] = {};
    int lrow = tid >> 2;        // m in tile, 0..63
    int lcol = (tid & 3) * 4;   // k in tile {0,4,8,12}
    int brow = tid >> 4;        // k in tile for B, 0..15
    int bcol = (tid & 15) * 4;  // n in tile

    for (int k0 = 0; k0 < KDIM; k0 += BK) {
        float4 av = *(const float4*)(A + (size_t)(bm + lrow) * KDIM + k0 + lcol);
        float4 bv = *(const float4*)(W + (size_t)(k0 + brow) * N + bn + bcol);
        __syncthreads();
        As[lcol + 0][lrow] = av.x;
        As[lcol + 1][lrow] = av.y;
        As[lcol + 2][lrow] = av.z;
        As[lcol + 3][lrow] = av.w;
        *(float4*)&Bs[brow][bcol] = bv;
        __syncthreads();
#pragma unroll
        for (int kk = 0; kk < BK; ++kk) {
            float4 a4 = *(const float4*)&As[kk][ty * 4];
            float4 b4 = *(const float4*)&Bs[kk][tx * 4];
            float a_[4] = {a4.x, a4.y, a4.z, a4.w};
            float b_[4] = {b4.x, b4.y, b4.z, b4.w};
#pragma unroll
            for (int i = 0; i < 4; ++i)
#pragma unroll
                for (int j = 0; j < 4; ++j) c[i][j] += a_[i] * b_[j];
        }
    }

    const float inv_bn = rsqrtf(1.0f + BN_EPS);
    int col0 = bn + tx * 4;
    float sc[4], bb[4], bt[4];
#pragma unroll
    for (int j = 0; j < 4; ++j) {
        sc[j] = gamma[col0 + j] * inv_bn;
        bb[j] = bias[col0 + j];
        bt[j] = beta[col0 + j];
    }
#pragma unroll
    for (int i = 0; i < 4; ++i) {
        int row = bm + ty * 4 + i;
        float4 o;
        o.x = fmaxf((c[i][0] + bb[0]) * sc[0] + bt[0], 0.f);
        o.y = fmaxf((c[i][1] + bb[1]) * sc[1] + bt[1], 0.f);
        o.z = fmaxf((c[i][2] + bb[2]) * sc[2] + bt[2], 0.f);
        o.w = fmaxf((c[i][3] + bb[3]) * sc[3] + bt[3], 0.f);
        *(float4*)(out + (size_t)row * N + col0) = o;
    }
}

// ---------------- K7: logits + log-softmax + CE gather -----------------------
// W3 [128][126] staged in LDS; 8 rows per block; 128 threads (thread j = class j).
__global__ __launch_bounds__(128) void k_dann(const float* __restrict__ h2,
                                              const float* __restrict__ W3,
                                              const float* __restrict__ b3,
                                              const int* __restrict__ pid,
                                              const int* __restrict__ mapped,
                                              float* __restrict__ scal) {
    __shared__ float Ws[H2_][P_];  // 64512 B
    __shared__ float hrow[H2_];
    __shared__ float wmax[2], wsum[2], wfin[2];
    int t = threadIdx.x;
    for (int i = t; i < H2_ * P_; i += 128) Ws[i / P_][i % P_] = W3[i];
    int r0 = blockIdx.x * 8;
    float partial = 0.f;
    for (int r = 0; r < 8; ++r) {
        int b = r0 + r;
        __syncthreads();  // protect hrow/Ws (first iter) + wmax/wsum reuse
        hrow[t] = h2[(size_t)b * H2_ + t];
        __syncthreads();
        float logit = -INFINITY;
        if (t < P_) {
            float acc = b3[t];
#pragma unroll 8
            for (int k = 0; k < H2_; ++k) acc += hrow[k] * Ws[k][t];
            logit = acc;
        }
        float m = logit;
        for (int off = 32; off; off >>= 1) m = fmaxf(m, __shfl_down(m, off, 64));
        if ((t & 63) == 0) wmax[t >> 6] = m;
        __syncthreads();
        float M = fmaxf(wmax[0], wmax[1]);
        float e = (t < P_) ? __expf(logit - M) : 0.f;
        float se = e;
        for (int off = 32; off; off >>= 1) se += __shfl_down(se, off, 64);
        if ((t & 63) == 0) wsum[t >> 6] = se;
        __syncthreads();
        float SE = wsum[0] + wsum[1];
        int mb = mapped[pid[b]];
        if (t == mb) partial += (M + __logf(SE) - logit);
    }
    float s = partial;
    for (int off = 32; off; off >>= 1) s += __shfl_down(s, off, 64);
    if ((t & 63) == 0) wfin[t >> 6] = s;
    __syncthreads();
    if (t == 0) atomicAdd(&scal[2], wfin[0] + wfin[1]);
}

// ---------------- K8: combine --------------------------------------------------
__global__ void k_final(const float* __restrict__ scal, float* __restrict__ out) {
    float within = scal[0];
    float between = scal[1];
    float dann = scal[2];
    out[0] = L_PCSL * (within / (between + EPS)) + L_DANN * (dann / (float)B_);
}

extern "C" void kernel_launch(void* const* d_in, const int* in_sizes, int n_in,
                              void* d_out, int out_size, void* d_ws, size_t ws_size,
                              hipStream_t stream) {
    const float* feat = (const float*)d_in[0];
    const int* pid = (const int*)d_in[1];
    const float* W1 = (const float*)d_in[2];
    const float* b1 = (const float*)d_in[3];
    const float* g1 = (const float*)d_in[4];
    const float* be1 = (const float*)d_in[5];
    const float* W2 = (const float*)d_in[6];
    const float* b2 = (const float*)d_in[7];
    const float* g2 = (const float*)d_in[8];
    const float* be2 = (const float*)d_in[9];
    const float* W3 = (const float*)d_in[10];
    const float* b3 = (const float*)d_in[11];
    float* out = (float*)d_out;

    // Workspace layout (16B aligned chunks)
    char* w = (char*)d_ws;
    float* f = (float*)w;                              // B*D
    float* cent = f + (size_t)B_ * D_;                 // P*D
    float* h1 = cent + (size_t)P_ * D_;                // B*H1
    float* h2 = h1 + (size_t)B_ * H1_;                 // B*H2
    float* sq = h2 + (size_t)B_ * H2_;                 // 128 (P rounded)
    float* counts = sq + 128;                          // 128
    float* scal = counts + 128;                        // 16 scalars
    int* mapped = (int*)(scal + 16);                   // P ints

    // zero the atomic accumulators (scal[0]=within, [1]=between, [2]=dann)
    hipMemsetAsync(scal, 0, 16 * sizeof(float), stream);

    k_mean<<<B_, 192, 0, stream>>>(feat, f);
    k_centroid<<<P_, 192, 0, stream>>>(f, pid, cent, sq, counts);
    k_between<<<1, 256, 0, stream>>>(cent, sq, counts, scal, mapped);
    k_within<<<512, 256, 0, stream>>>(f, pid, cent, scal);
    k_gemm_bn_relu<D_><<<dim3(B_ / 64, H1_ / 64), 256, 0, stream>>>(f, W1, b1, g1, be1, h1, H1_);
    k_gemm_bn_relu<H1_><<<dim3(B_ / 64, H2_ / 64), 256, 0, stream>>>(h1, W2, b2, g2, be2, h2, H2_);
    k_dann<<<B_ / 8, 128, 0, stream>>>(h2, W3, b3, pid, mapped, scal);
    k_final<<<1, 1, 0, stream>>>(scal, out);
}